// Round 6
// baseline (50.336 us; speedup 1.0000x reference)
//
#include <hip/hip_runtime.h>

// out[n,m] = -sum_d |x[n,d]-y[m,d]|  N=M=2048, D=128, fp32.  VALU-bound.
// R4 post-mortem: SMEM x-path can't pipeline (out-of-order returns force
// lgkmcnt(0) per row) and allocator dropped y residency (VGPR=32, FETCH 2x).
// R5: x through LDS BROADCAST (uniform-addr ds_read_b128: 1 bank cycle,
// in-order lgkmcnt -> compiler pipelines), y per-lane in VGPRs with the
// budget pinned by __launch_bounds__(256,4) (=128 VGPR cap, need ~90).
// Block = 4 waves, 32 rows x 128 cols; x tile (16KB) staged once, 1 barrier.
// 1024 blocks = 4/CU = 4 waves/SIMD. VALU floor 13.7us.

typedef float f4 __attribute__((ext_vector_type(4)));

#define DD 128
#define BR 32     // rows per block
#define ROWS 16   // rows per wave
#define NCH 4     // y-chunks of 32 floats

__launch_bounds__(256, 4)
__global__ void l1_dist_kernel(const float* __restrict__ X,
                               const float* __restrict__ Y,
                               float* __restrict__ out,
                               int N, int M) {
    __shared__ float xs[BR * DD];   // 16 KB

    const int tid = threadIdx.x;
    const int wave = tid >> 6;
    const int lane = tid & 63;
    const int brow = blockIdx.y * BR;
    const int bcol = blockIdx.x * 128;
    const int wrow = (wave >> 1) * ROWS;            // 0 or 16 (block-local)
    const int m = bcol + (wave & 1) * 64 + lane;    // this lane's column

    // Stage x tile: 32 rows x 128 floats = 1024 f4; 256 threads -> 4 each.
    // Coalesced (consecutive threads -> consecutive 16B), once per block.
#pragma unroll
    for (int k = 0; k < 4; ++k) {
        int idx = tid + k * 256;
        int r = idx >> 5, q = idx & 31;
        *(f4*)&xs[r * DD + (q << 2)] =
            *(const f4*)&X[(size_t)(brow + r) * DD + (q << 2)];
    }
    __syncthreads();

    float acc[ROWS];
#pragma unroll
    for (int r = 0; r < ROWS; ++r) acc[r] = 0.f;

#pragma unroll 1   // keep chunks sequential: don't hoist 4 chunks of y regs
    for (int c = 0; c < NCH; ++c) {
        // This lane's y chunk: 32 floats = 8 f4 = 32 VGPR. L2-hot load.
        f4 yv[8];
        const f4* yp = (const f4*)(Y + (size_t)m * DD + c * 32);
#pragma unroll
        for (int k = 0; k < 8; ++k) yv[k] = yp[k];

#pragma unroll
        for (int r = 0; r < ROWS; ++r) {
            // Wave-uniform address -> ds_read_b128 broadcast, pipelined.
            const f4* xp = (const f4*)&xs[(wrow + r) * DD + c * 32];
            float a0 = 0.f, a1 = 0.f, a2 = 0.f, a3 = 0.f;
#pragma unroll
            for (int k = 0; k < 8; ++k) {
                f4 xv = xp[k];
                a0 += __builtin_fabsf(xv.x - yv[k].x);
                a1 += __builtin_fabsf(xv.y - yv[k].y);
                a2 += __builtin_fabsf(xv.z - yv[k].z);
                a3 += __builtin_fabsf(xv.w - yv[k].w);
            }
            acc[r] += (a0 + a1) + (a2 + a3);
        }
    }

#pragma unroll
    for (int r = 0; r < ROWS; ++r)
        out[(size_t)(brow + wrow + r) * M + m] = -acc[r];  // 256B/wave store
}

extern "C" void kernel_launch(void* const* d_in, const int* in_sizes, int n_in,
                              void* d_out, int out_size, void* d_ws, size_t ws_size,
                              hipStream_t stream) {
    const float* x = (const float*)d_in[0];
    const float* y = (const float*)d_in[1];
    float* out = (float*)d_out;
    const int N = in_sizes[0] / DD;   // 2048
    const int M = in_sizes[1] / DD;   // 2048
    dim3 grid(M / 128, N / BR);       // (16, 64) = 1024 blocks
    l1_dist_kernel<<<grid, 256, 0, stream>>>(x, y, out, N, M);
}